// Round 15
// baseline (206.091 us; speedup 1.0000x reference)
//
#include <hip/hip_runtime.h>
#include <stdint.h>
#include <math.h>

#define A_N 65536
#define B_N 16
#define T_N 64
#define NB  (A_N / 256)      // k1 blocks per image = 256 (1 anchor/thread)
#define EPSF 1e-6f
#define LN2F   0.69314718055994531f
#define LOG2EF 1.4426950408889634f

// fast hw ops: v_exp_f32 (2^x), v_log_f32 (log2 x), v_rcp_f32, v_sqrt_f32
#define EXP2F(x) __builtin_amdgcn_exp2f(x)
#define LOG2F(x) __builtin_amdgcn_logf(x)
#define RCPF(x)  __builtin_amdgcn_rcpf(x)
#define SQRTF(x) __builtin_amdgcn_sqrtf(x)

// ---------------------------------------------------------------------------
// Workspace (same as r10/r14):
//   keys     : B * NB * 64 * u64 = 2 MiB   @ 0          (hi=iou bits, lo=~anchor)
//   code     : B * A * u8        = 1 MiB   @ 2 MiB      (bt | thr<<7)
//   partials : B * NB * float4   = 64 KiB  @ 3 MiB      (conf, ct, bbox, cls)
//   lossImg  : B * 3 * f32       = 192 B   @ 3 MiB+64K
//   done     : u32               = 4 B     @ 3 MiB+64K+256  (reset by k1)
// ---------------------------------------------------------------------------

__device__ __forceinline__ float iou_fast(float4 an, float a1, float4 t4, float tar)
{
    float x1 = fmaxf(an.x, t4.x), y1 = fmaxf(an.y, t4.y);
    float x2 = fminf(an.z, t4.z), y2 = fminf(an.w, t4.w);
    float inter = fmaxf(x2 - x1, 0.f) * fmaxf(y2 - y1, 0.f);
    float ue = ((a1 + tar) - inter) + EPSF;          // np-exact association
    return inter * RCPF(ue);
}

__device__ __forceinline__ float conf_term(float p, bool pos)
{
    float u = pos ? p : (1.f - p);
    float w = 1.f - u;
    float bce = -LN2F * LOG2F(u + EPSF);
    float fw = w * SQRTF(w);             // w^1.5
    return bce * fw * 0.5f;              // alpha factor == 0.5
}

__device__ __forceinline__ float softplus_negabs(float x)
{
    float y = EXP2F(fabsf(x) * -LOG2EF);
    return LN2F * LOG2F(1.0f + y);
}

__device__ __forceinline__ float cls_term(const float4* cp, const float* cls_f,
                                          size_t ba, int lab)
{
    float s2 = 0.f;
    #pragma unroll
    for (int q = 0; q < 5; ++q) {
        float4 v = cp[q];
        s2 += fmaxf(v.x, 0.f) + softplus_negabs(v.x);
        s2 += fmaxf(v.y, 0.f) + softplus_negabs(v.y);
        s2 += fmaxf(v.z, 0.f) + softplus_negabs(v.z);
        s2 += fmaxf(v.w, 0.f) + softplus_negabs(v.w);
    }
    float xl = cls_f[ba * 20 + (size_t)lab];
    return (s2 - xl) * (1.f / 20.f);
}

__device__ __forceinline__ float bterm_at(float4 pb, float4 mb)
{
    float x1 = fmaxf(pb.x, mb.x), y1 = fmaxf(pb.y, mb.y);
    float x2 = fminf(pb.z, mb.z), y2 = fminf(pb.w, mb.w);
    float inter = fmaxf(x2 - x1, 0.f) * fmaxf(y2 - y1, 0.f);
    float pa1 = (pb.z - pb.x) * (pb.w - pb.y);
    float pa2 = (mb.z - mb.x) * (mb.w - mb.y);
    float uni = pa1 + pa2 - inter;
    float iou = inter * RCPF(uni + EPSF);
    float ex1 = fminf(pb.x, mb.x), ey1 = fminf(pb.y, mb.y);
    float ex2 = fmaxf(pb.z, mb.z), ey2 = fmaxf(pb.w, mb.w);
    float enc = (ex2 - ex1) * (ey2 - ey1);
    float giou = iou - (enc - uni) * RCPF(enc + EPSF);
    float l1 = 0.25f * (fabsf(pb.x - mb.x) + fabsf(pb.y - mb.y) +
                        fabsf(pb.z - mb.z) + fabsf(pb.w - mb.w));
    return (1.f - giou) + 0.5f * l1;
}

// resolve over grid mask with inter>0 prefilter: non-intersecting targets
// cost only the b128 read + intersect test. inter==0 pairs cannot update
// bb (u=0) nor pass the candidate gate -> identical selection to r14.
__device__ __forceinline__ void resolve_p1(
    unsigned int w, int base, float4 an, float a1, float npa,
    const float4* tb, const float* ta,
    unsigned int* slot_hi, unsigned int& bb, int& bt, unsigned int& m2)
{
    m2 = 0u;
    while (w) {
        int z = __builtin_clz(w);               // ascending s = first-max
        unsigned int bit = 0x80000000u >> z;
        w &= ~bit;
        int s = base + z;
        float4 t4 = tb[s];
        float x1 = fmaxf(an.x, t4.x), y1 = fmaxf(an.y, t4.y);
        float x2 = fminf(an.z, t4.z), y2 = fminf(an.w, t4.w);
        float inter = fmaxf(x2 - x1, 0.f) * fmaxf(y2 - y1, 0.f);
        if (inter > 0.f) {
            float tas = ta[s];
            float ue = ((a1 + tas) - inter) + EPSF;
            float iou = inter * RCPF(ue);
            unsigned int u = __float_as_uint(iou);
            if (u > bb) { bb = u; bt = s; }
            // gate: iou >= ~0.2493 (same margin class as rhsv precompute)
            if (fmaf(1.2493f, inter, npa) >= fmaf(0.2493f, tas, 0.2493e-6f)) {
                unsigned int old = atomicMax(&slot_hi[s], u);
                if (u >= old) m2 |= bit;        // running max -> possible winner
            }
        }
    }
}

// pass2: among final-max achievers, max ~anchor (= min anchor index)
__device__ __forceinline__ void resolve_p2(
    unsigned int m2, int base, float4 an, float a1,
    const float4* tb, const float* ta, const unsigned int* slot_hi,
    unsigned int* slot_lo, unsigned int lo)
{
    while (m2) {
        int z = __builtin_clz(m2);
        m2 &= ~(0x80000000u >> z);
        int s = base + z;
        float iou = iou_fast(an, a1, tb[s], ta[s]);
        if (__float_as_uint(iou) == slot_hi[s]) atomicMax(&slot_lo[s], lo);
    }
}

// K1: 8x8 cell->target u64 bitmask grid; resolve on masked targets with
//     inter>0 prefilter. Fused losses under pos:=thr.
__global__ __launch_bounds__(256) void k1_main(
    const float4* __restrict__ anchors,
    const float4* __restrict__ bbox,
    const float*  __restrict__ conf,
    const float4* __restrict__ cls,       // 20 floats/anchor = 5 x float4
    const float4* __restrict__ tboxes,
    const int*    __restrict__ tlabels,
    unsigned long long* __restrict__ keys,
    unsigned char* __restrict__ code,
    float4* __restrict__ partials,
    unsigned int* __restrict__ done)
{
    __shared__ float4 tb[T_N];
    __shared__ float  ta[T_N];
    __shared__ int    tl[T_N];
    __shared__ unsigned int slot_hi[T_N];
    __shared__ unsigned int slot_lo[T_N];
    __shared__ uint2 cellm[64];              // 8x8 grid: .x=targets 0..31, .y=32..63
    const int b   = blockIdx.y;
    const int tid = threadIdx.x;
    if (tid < T_N) {
        float4 t = tboxes[b * T_N + tid];
        float ar = (t.z - t.x) * (t.w - t.y);
        tb[tid] = t;
        ta[tid] = ar;
        tl[tid] = tlabels[b * T_N + tid];
        slot_hi[tid] = 0u;
        slot_lo[tid] = 0u;
        cellm[tid] = make_uint2(0u, 0u);
    }
    if (tid == 0 && blockIdx.x == 0 && b == 0) *done = 0u;  // reset for k2
    __syncthreads();

    // build cell masks: thread = (cell, 16-target group); inclusive tests
    {
        const int c  = tid & 63;
        const int pr = tid >> 6;               // 0..3
        const int cx = c & 7, cy = c >> 3;
        const float clx = cx * 0.125f, chx = clx + 0.125f;
        const float cly = cy * 0.125f, chy = cly + 0.125f;
        unsigned int pm = 0u;
        const int t0 = pr * 16;
        #pragma unroll
        for (int j = 0; j < 16; ++j) {
            int t = t0 + j;
            float4 t4 = tb[t];
            bool hit = (t4.x <= chx) && (t4.z >= clx) &&
                       (t4.y <= chy) && (t4.w >= cly);
            pm |= hit ? (0x80000000u >> (t & 31)) : 0u;
        }
        if (pr < 2) atomicOr(&cellm[c].x, pm);
        else        atomicOr(&cellm[c].y, pm);
    }
    __syncthreads();

    const int a = blockIdx.x * 256 + tid;
    const size_t ba = (size_t)b * A_N + a;
    const float4 an = anchors[a];
    const float a1 = (an.z - an.x) * (an.w - an.y);
    const float npa = -0.2493f * a1;
    const unsigned int lo = ~(unsigned int)a;   // smaller idx -> larger lo

    // gather target mask from the cells this anchor's box touches (<=3x3)
    unsigned int mlo = 0u, mhi = 0u;
    {
        const int cx0 = min(7, (int)(an.x * 8.f));
        const int cx1 = min(7, (int)(an.z * 8.f));
        const int cy0 = min(7, (int)(an.y * 8.f));
        const int cy1 = min(7, (int)(an.w * 8.f));
        for (int cy = cy0; cy <= cy1; ++cy)
            for (int cx = cx0; cx <= cx1; ++cx) {
                uint2 m = cellm[cy * 8 + cx];   // ds_read_b64
                mlo |= m.x;
                mhi |= m.y;
            }
    }

    unsigned int bb = 0u; int bt = 0;
    unsigned int m2lo, m2hi;
    resolve_p1(mlo,  0, an, a1, npa, tb, ta, slot_hi, bb, bt, m2lo);
    resolve_p1(mhi, 32, an, a1, npa, tb, ta, slot_hi, bb, bt, m2hi);
    __syncthreads();
    resolve_p2(m2lo,  0, an, a1, tb, ta, slot_hi, slot_lo, lo);
    resolve_p2(m2hi, 32, an, a1, tb, ta, slot_hi, slot_lo, lo);

    const bool thr = (bb >= 0x3F000000u);       // max iou >= 0.5
    code[ba] = (unsigned char)(bt | (thr ? 128 : 0));

    float r0 = conf_term(conf[ba], thr);
    float r2 = 0.f, r3 = 0.f;
    if (thr) {                                  // exec-masked once per wave
        r2 = bterm_at(bbox[ba], tb[bt]);
        r3 = cls_term(cls + ba * 5, (const float*)cls, ba, tl[bt] - 1);
    }
    const float r1 = (float)__popcll(__ballot(thr));   // pos count

    #pragma unroll
    for (int off = 32; off; off >>= 1) {
        r0 += __shfl_down(r0, off, 64);
        r2 += __shfl_down(r2, off, 64);
        r3 += __shfl_down(r3, off, 64);
    }
    __shared__ float4 red[4];
    const int wv = tid >> 6;
    if ((tid & 63) == 0) red[wv] = make_float4(r0, r1, r2, r3);
    __syncthreads();   // also fences pass-2 atomics before slot readback
    if (tid == 0) {
        float4 v;
        v.x = red[0].x + red[1].x + red[2].x + red[3].x;
        v.y = red[0].y + red[1].y + red[2].y + red[3].y;
        v.z = red[0].z + red[1].z + red[2].z + red[3].z;
        v.w = red[0].w + red[1].w + red[2].w + red[3].w;
        partials[(size_t)b * NB + blockIdx.x] = v;
    }
    if (tid < T_N)
        keys[(((size_t)b * NB + blockIdx.x) << 6) | tid] =
            ((unsigned long long)slot_hi[tid] << 32) | (unsigned long long)slot_lo[tid];
}

// K2: per image — winners + exact fallback + forced-only corrections +
//     per-image finalize; last block averages across images -> out[4].
__global__ __launch_bounds__(1024) void k2_all(
    const unsigned long long* __restrict__ keys,
    const float4* __restrict__ anchors,
    const float4* __restrict__ bbox,
    const float*  __restrict__ conf,
    const float4* __restrict__ cls,
    const float4* __restrict__ tboxes,
    const int*    __restrict__ tlabels,
    const unsigned char* __restrict__ code,
    const float4* __restrict__ partials,
    float* __restrict__ lossImg,
    unsigned int* __restrict__ done,
    float* __restrict__ out)
{
    __shared__ unsigned long long sh[16][64];
    __shared__ unsigned long long sw[16];
    __shared__ float4 tb[T_N];
    __shared__ float  ta[T_N];
    __shared__ unsigned int winner[64];
    __shared__ int emptyList[64];
    __shared__ int nEmpty;
    __shared__ float4 corr;
    __shared__ float4 redf[4];
    __shared__ int lastFlag;
    const int b = blockIdx.x, tid = threadIdx.x;
    const int t = tid & 63, g = tid >> 6;
    if (tid == 0) nEmpty = 0;
    if (tid < T_N) {
        float4 tt = tboxes[b * T_N + tid];
        tb[tid] = tt;
        ta[tid] = (tt.z - tt.x) * (tt.w - tt.y);
    }

    unsigned long long K = 0ull;
    #pragma unroll 4
    for (int i = 0; i < 16; ++i) {
        unsigned long long k = keys[(((size_t)b * NB + (g * 16 + i)) << 6) | t];
        if (k > K) K = k;
    }
    sh[g][t] = K;
    __syncthreads();
    if (tid < 64) {
        unsigned long long m = sh[0][tid];
        #pragma unroll
        for (int g2 = 1; g2 < 16; ++g2) if (sh[g2][tid] > m) m = sh[g2][tid];
        unsigned int lo32 = (unsigned int)(m & 0xFFFFFFFFull);
        if (lo32 != 0u) winner[tid] = ~lo32;
        else { int i = atomicAdd(&nEmpty, 1); emptyList[i] = tid; }
    }
    __syncthreads();

    const int ne = nEmpty;            // normally 0
    for (int e = 0; e < ne; ++e) {
        const int tt = emptyList[e];
        const float4 tbx = tb[tt];
        const float tar = ta[tt];
        unsigned long long bk = 0ull;
        for (int i = tid; i < A_N; i += 1024) {
            float4 an = anchors[i];
            float a1 = (an.z - an.x) * (an.w - an.y);
            float iou = iou_fast(an, a1, tbx, tar);
            unsigned long long key = ((unsigned long long)__float_as_uint(iou) << 32)
                                   | (unsigned long long)(~(unsigned int)i);
            if (key > bk) bk = key;
        }
        #pragma unroll
        for (int off = 32; off; off >>= 1) {
            unsigned long long o = __shfl_down(bk, off, 64);
            if (o > bk) bk = o;
        }
        if ((tid & 63) == 0) sw[g] = bk;
        __syncthreads();
        if (tid == 0) {
            unsigned long long m = sw[0];
            #pragma unroll
            for (int i = 1; i < 16; ++i) if (sw[i] > m) m = sw[i];
            winner[tt] = ~(unsigned int)(m & 0xFFFFFFFFull);
        }
        __syncthreads();
    }

    // corrections: first wave, dedupe winners (lowest target owns), exact
    // row-argmax recompute for matched target.
    if (tid < 64) {
        const unsigned int wa = winner[tid];
        bool owner = true;
        for (int k = 0; k < 64; ++k) {
            unsigned int o = __shfl(wa, k, 64);
            if (k < tid && o == wa) owner = false;
        }
        const size_t ba = (size_t)b * A_N + wa;
        float d0 = 0.f, d1 = 0.f, d2 = 0.f, d3 = 0.f;
        if (owner && (code[ba] & 128) == 0) {
            const float4 aw = anchors[wa];
            const float aw1 = (aw.z - aw.x) * (aw.w - aw.y);
            unsigned int bb = 0u; int bt = 0;
            for (int s = 0; s < T_N; ++s) {
                float iou = iou_fast(aw, aw1, tb[s], ta[s]);
                unsigned int u = __float_as_uint(iou);
                if (u > bb) { bb = u; bt = s; }
            }
            const float p = conf[ba];
            d0 = conf_term(p, true) - conf_term(p, false);   // f0 cancels k1's term
            d1 = 1.f;
            d2 = bterm_at(bbox[ba], tb[bt]);
            d3 = cls_term(cls + ba * 5, (const float*)cls, ba,
                          tlabels[b * T_N + bt] - 1);
        }
        #pragma unroll
        for (int off = 32; off; off >>= 1) {
            d0 += __shfl_down(d0, off, 64);
            d1 += __shfl_down(d1, off, 64);
            d2 += __shfl_down(d2, off, 64);
            d3 += __shfl_down(d3, off, 64);
        }
        if (tid == 0) corr = make_float4(d0, d1, d2, d3);
    }
    __syncthreads();

    // finalize this image: sum 256 float4 partials + corr
    if (tid < NB) {
        float4 v = partials[(size_t)b * NB + tid];
        #pragma unroll
        for (int off = 32; off; off >>= 1) {
            v.x += __shfl_down(v.x, off, 64);
            v.y += __shfl_down(v.y, off, 64);
            v.z += __shfl_down(v.z, off, 64);
            v.w += __shfl_down(v.w, off, 64);
        }
        if ((tid & 63) == 0) redf[tid >> 6] = v;
    }
    __syncthreads();
    if (tid == 0) {
        float s0 = redf[0].x + redf[1].x + redf[2].x + redf[3].x + corr.x;
        float s1 = redf[0].y + redf[1].y + redf[2].y + redf[3].y + corr.y;
        float s2 = redf[0].z + redf[1].z + redf[2].z + redf[3].z + corr.z;
        float s3 = redf[0].w + redf[1].w + redf[2].w + redf[3].w + corr.w;
        float npos = fmaxf(s1, 1.f);
        // device-coherent writes (atomic path bypasses L1; cross-XCD safe)
        atomicExch(&lossImg[b * 3 + 0], s0 * (1.f / (float)A_N));
        atomicExch(&lossImg[b * 3 + 1], s2 / npos);
        atomicExch(&lossImg[b * 3 + 2], s3 / npos);
        __threadfence();
        unsigned int old = atomicAdd(done, 1u);
        lastFlag = (old == B_N - 1) ? 1 : 0;
    }
    __syncthreads();

    // last image-block averages all 16 images -> out[4]
    if (lastFlag && tid < 64) {
        __threadfence();
        float c = 0.f, bm = 0.f, l = 0.f;
        if (tid < B_N) {
            c  = atomicAdd(&lossImg[tid * 3 + 0], 0.f);   // coherent read
            bm = atomicAdd(&lossImg[tid * 3 + 1], 0.f);
            l  = atomicAdd(&lossImg[tid * 3 + 2], 0.f);
        }
        #pragma unroll
        for (int off = 8; off; off >>= 1) {
            c  += __shfl_down(c,  off, 64);
            bm += __shfl_down(bm, off, 64);
            l  += __shfl_down(l,  off, 64);
        }
        if (tid == 0) {
            c *= (1.f / 16.f); bm *= (1.f / 16.f); l *= (1.f / 16.f);
            out[0] = c + bm + l;
            out[1] = c;
            out[2] = bm;
            out[3] = l;
        }
    }
}

extern "C" void kernel_launch(void* const* d_in, const int* in_sizes, int n_in,
                              void* d_out, int out_size, void* d_ws, size_t ws_size,
                              hipStream_t stream)
{
    const float4* bbox    = (const float4*)d_in[0];
    const float*  conf    = (const float*) d_in[1];
    const float4* cls     = (const float4*)d_in[2];
    const float4* anchors = (const float4*)d_in[3];
    const float4* tboxes  = (const float4*)d_in[4];
    const int*    tlabels = (const int*)   d_in[5];
    float* out = (float*)d_out;

    char* ws = (char*)d_ws;
    unsigned long long* keys  = (unsigned long long*)ws;                   // 2 MiB
    unsigned char*      code  = (unsigned char*)(ws + (2u << 20));         // 1 MiB
    float4*       partials = (float4*)(ws + (3u << 20));                   // 64 KiB
    float*        lossImg  = (float*)(ws + (3u << 20) + (64u << 10));      // 192 B
    unsigned int* done     = (unsigned int*)(ws + (3u << 20) + (64u << 10) + 256);

    k1_main <<<dim3(NB, B_N), 256, 0, stream>>>(anchors, bbox, conf, cls, tboxes,
                                                tlabels, keys, code, partials, done);
    k2_all  <<<B_N, 1024, 0, stream>>>(keys, anchors, bbox, conf, cls, tboxes,
                                       tlabels, code, partials, lossImg, done, out);
}

// Round 16
// 52.415 us; speedup vs baseline: 3.9320x; 3.9320x over previous
//
#include <hip/hip_runtime.h>
#include <stdint.h>
#include <math.h>

#define A_N 65536
#define B_N 16
#define T_N 64
#define NB  (A_N / 256)      // k1 blocks per image = 256 (1 anchor/thread)
#define EPSF 1e-6f
#define LN2F   0.69314718055994531f
#define LOG2EF 1.4426950408889634f

// fast hw ops: v_exp_f32 (2^x), v_log_f32 (log2 x), v_rcp_f32, v_sqrt_f32
#define EXP2F(x) __builtin_amdgcn_exp2f(x)
#define LOG2F(x) __builtin_amdgcn_logf(x)
#define RCPF(x)  __builtin_amdgcn_rcpf(x)
#define SQRTF(x) __builtin_amdgcn_sqrtf(x)

// ---------------------------------------------------------------------------
// Workspace (same as r10/r14):
//   keys     : B * NB * 64 * u64 = 2 MiB   @ 0          (hi=iou bits, lo=~anchor)
//   code     : B * A * u8        = 1 MiB   @ 2 MiB      (bt | thr<<7)
//   partials : B * NB * float4   = 64 KiB  @ 3 MiB      (conf, ct, bbox, cls)
//   lossImg  : B * 3 * f32       = 192 B   @ 3 MiB+64K
//   done     : u32               = 4 B     @ 3 MiB+64K+256  (reset by k1)
// ---------------------------------------------------------------------------

__device__ __forceinline__ float iou_fast(float4 an, float a1, float4 t4, float tar)
{
    float x1 = fmaxf(an.x, t4.x), y1 = fmaxf(an.y, t4.y);
    float x2 = fminf(an.z, t4.z), y2 = fminf(an.w, t4.w);
    float inter = fmaxf(x2 - x1, 0.f) * fmaxf(y2 - y1, 0.f);
    float ue = ((a1 + tar) - inter) + EPSF;          // np-exact association
    return inter * RCPF(ue);
}

__device__ __forceinline__ float conf_term(float p, bool pos)
{
    float u = pos ? p : (1.f - p);
    float w = 1.f - u;
    float bce = -LN2F * LOG2F(u + EPSF);
    float fw = w * SQRTF(w);             // w^1.5
    return bce * fw * 0.5f;              // alpha factor == 0.5
}

__device__ __forceinline__ float softplus_negabs(float x)
{
    float y = EXP2F(fabsf(x) * -LOG2EF);
    return LN2F * LOG2F(1.0f + y);
}

__device__ __forceinline__ float cls_term(const float4* cp, const float* cls_f,
                                          size_t ba, int lab)
{
    float s2 = 0.f;
    #pragma unroll
    for (int q = 0; q < 5; ++q) {
        float4 v = cp[q];
        s2 += fmaxf(v.x, 0.f) + softplus_negabs(v.x);
        s2 += fmaxf(v.y, 0.f) + softplus_negabs(v.y);
        s2 += fmaxf(v.z, 0.f) + softplus_negabs(v.z);
        s2 += fmaxf(v.w, 0.f) + softplus_negabs(v.w);
    }
    float xl = cls_f[ba * 20 + (size_t)lab];
    return (s2 - xl) * (1.f / 20.f);
}

__device__ __forceinline__ float bterm_at(float4 pb, float4 mb)
{
    float x1 = fmaxf(pb.x, mb.x), y1 = fmaxf(pb.y, mb.y);
    float x2 = fminf(pb.z, mb.z), y2 = fminf(pb.w, mb.w);
    float inter = fmaxf(x2 - x1, 0.f) * fmaxf(y2 - y1, 0.f);
    float pa1 = (pb.z - pb.x) * (pb.w - pb.y);
    float pa2 = (mb.z - mb.x) * (mb.w - mb.y);
    float uni = pa1 + pa2 - inter;
    float iou = inter * RCPF(uni + EPSF);
    float ex1 = fminf(pb.x, mb.x), ey1 = fminf(pb.y, mb.y);
    float ex2 = fmaxf(pb.z, mb.z), ey2 = fmaxf(pb.w, mb.w);
    float enc = (ex2 - ex1) * (ey2 - ey1);
    float giou = iou - (enc - uni) * RCPF(enc + EPSF);
    float l1 = 0.25f * (fabsf(pb.x - mb.x) + fabsf(pb.y - mb.y) +
                        fabsf(pb.z - mb.z) + fabsf(pb.w - mb.w));
    return (1.f - giou) + 0.5f * l1;
}

// single-pass resolve over grid mask: first-max tracking for ALL intersecting
// targets; candidate-gated u64 LDS atomicMax (no pass2, no equality linkage).
// inter==0 cannot pass the gate -> prefilter is selection-neutral.
__device__ __forceinline__ void resolve(
    unsigned int w, int base, float4 an, float a1, float npa,
    const float4* tb, const float* ta, const float* rhsv,
    unsigned long long* slot, unsigned int anlo,
    unsigned int& bb, int& bt)
{
    while (w) {
        int z = __builtin_clz(w);               // ascending s = first-max
        unsigned int bit = 0x80000000u >> z;
        w &= ~bit;
        int s = base + z;
        float4 t4 = tb[s];
        float x1 = fmaxf(an.x, t4.x), y1 = fmaxf(an.y, t4.y);
        float x2 = fminf(an.z, t4.z), y2 = fminf(an.w, t4.w);
        float inter = fmaxf(x2 - x1, 0.f) * fmaxf(y2 - y1, 0.f);
        if (inter > 0.f) {
            float ue = ((a1 + ta[s]) - inter) + EPSF;
            float iou = inter * RCPF(ue);
            unsigned int u = __float_as_uint(iou);
            if (u > bb) { bb = u; bt = s; }
            if (fmaf(1.2493f, inter, npa) >= rhsv[s]) {     // candidate gate
                unsigned long long key = ((unsigned long long)u << 32)
                                       | (unsigned long long)anlo;
                atomicMax(&slot[s], key);       // rare (~0.45/anchor): CAS ok
            }
        }
    }
}

// K1: 8x8 cell->target bitmask grid; single-pass u64-atomicMax resolve on
//     masked targets with inter>0 prefilter. Fused losses under pos:=thr.
__global__ __launch_bounds__(256) void k1_main(
    const float4* __restrict__ anchors,
    const float4* __restrict__ bbox,
    const float*  __restrict__ conf,
    const float4* __restrict__ cls,       // 20 floats/anchor = 5 x float4
    const float4* __restrict__ tboxes,
    const int*    __restrict__ tlabels,
    unsigned long long* __restrict__ keys,
    unsigned char* __restrict__ code,
    float4* __restrict__ partials,
    unsigned int* __restrict__ done)
{
    __shared__ float4 tb[T_N];
    __shared__ float  ta[T_N];
    __shared__ float  rhsv[T_N];
    __shared__ int    tl[T_N];
    __shared__ unsigned long long slot[T_N];
    __shared__ unsigned int cellm_lo[64];    // 8x8 grid: targets (0..31)
    __shared__ unsigned int cellm_hi[64];    //           targets (32..63)
    const int b   = blockIdx.y;
    const int tid = threadIdx.x;
    if (tid < T_N) {
        float4 t = tboxes[b * T_N + tid];
        float ar = (t.z - t.x) * (t.w - t.y);
        tb[tid] = t;
        ta[tid] = ar;
        rhsv[tid] = 0.2493f * (ar + EPSF);      // candidate-test rhs
        tl[tid] = tlabels[b * T_N + tid];
        slot[tid] = 0ull;
        cellm_lo[tid] = 0u;
        cellm_hi[tid] = 0u;
    }
    if (tid == 0 && blockIdx.x == 0 && b == 0) *done = 0u;  // reset for k2
    __syncthreads();

    // build cell masks: thread = (cell, 16-target group); inclusive tests
    {
        const int c  = tid & 63;
        const int pr = tid >> 6;               // 0..3
        const int cx = c & 7, cy = c >> 3;
        const float clx = cx * 0.125f, chx = clx + 0.125f;
        const float cly = cy * 0.125f, chy = cly + 0.125f;
        unsigned int pm = 0u;
        const int t0 = pr * 16;
        #pragma unroll
        for (int j = 0; j < 16; ++j) {
            int t = t0 + j;
            float4 t4 = tb[t];
            bool hit = (t4.x <= chx) && (t4.z >= clx) &&
                       (t4.y <= chy) && (t4.w >= cly);
            pm |= hit ? (0x80000000u >> (t & 31)) : 0u;
        }
        if (pr < 2) atomicOr(&cellm_lo[c], pm);
        else        atomicOr(&cellm_hi[c], pm);
    }
    __syncthreads();

    const int a = blockIdx.x * 256 + tid;
    const size_t ba = (size_t)b * A_N + a;
    const float4 an = anchors[a];
    const float a1 = (an.z - an.x) * (an.w - an.y);
    const float npa = -0.2493f * a1;
    const unsigned int lo = ~(unsigned int)a;   // smaller idx -> larger lo

    // gather target mask from the cells this anchor's box touches (<=3x3)
    unsigned int mlo = 0u, mhi = 0u;
    {
        const int cx0 = min(7, (int)(an.x * 8.f));
        const int cx1 = min(7, (int)(an.z * 8.f));
        const int cy0 = min(7, (int)(an.y * 8.f));
        const int cy1 = min(7, (int)(an.w * 8.f));
        for (int cy = cy0; cy <= cy1; ++cy)
            for (int cx = cx0; cx <= cx1; ++cx) {
                int c = cy * 8 + cx;
                mlo |= cellm_lo[c];
                mhi |= cellm_hi[c];
            }
    }

    unsigned int bb = 0u; int bt = 0;
    resolve(mlo,  0, an, a1, npa, tb, ta, rhsv, slot, lo, bb, bt);
    resolve(mhi, 32, an, a1, npa, tb, ta, rhsv, slot, lo, bb, bt);

    const bool thr = (bb >= 0x3F000000u);       // max iou >= 0.5
    code[ba] = (unsigned char)(bt | (thr ? 128 : 0));

    float r0 = conf_term(conf[ba], thr);
    float r2 = 0.f, r3 = 0.f;
    if (thr) {                                  // exec-masked once per wave
        r2 = bterm_at(bbox[ba], tb[bt]);
        r3 = cls_term(cls + ba * 5, (const float*)cls, ba, tl[bt] - 1);
    }
    const float r1 = (float)__popcll(__ballot(thr));   // pos count

    #pragma unroll
    for (int off = 32; off; off >>= 1) {
        r0 += __shfl_down(r0, off, 64);
        r2 += __shfl_down(r2, off, 64);
        r3 += __shfl_down(r3, off, 64);
    }
    __shared__ float4 red[4];
    const int wv = tid >> 6;
    if ((tid & 63) == 0) red[wv] = make_float4(r0, r1, r2, r3);
    __syncthreads();   // also fences all slot atomics before readback
    if (tid == 0) {
        float4 v;
        v.x = red[0].x + red[1].x + red[2].x + red[3].x;
        v.y = red[0].y + red[1].y + red[2].y + red[3].y;
        v.z = red[0].z + red[1].z + red[2].z + red[3].z;
        v.w = red[0].w + red[1].w + red[2].w + red[3].w;
        partials[(size_t)b * NB + blockIdx.x] = v;
    }
    if (tid < T_N)
        keys[(((size_t)b * NB + blockIdx.x) << 6) | tid] = slot[tid];
}

// K2: per image — winners + exact fallback + forced-only corrections +
//     per-image finalize; last block averages across images -> out[4].
__global__ __launch_bounds__(1024) void k2_all(
    const unsigned long long* __restrict__ keys,
    const float4* __restrict__ anchors,
    const float4* __restrict__ bbox,
    const float*  __restrict__ conf,
    const float4* __restrict__ cls,
    const float4* __restrict__ tboxes,
    const int*    __restrict__ tlabels,
    const unsigned char* __restrict__ code,
    const float4* __restrict__ partials,
    float* __restrict__ lossImg,
    unsigned int* __restrict__ done,
    float* __restrict__ out)
{
    __shared__ unsigned long long sh[16][64];
    __shared__ unsigned long long sw[16];
    __shared__ float4 tb[T_N];
    __shared__ float  ta[T_N];
    __shared__ unsigned int winner[64];
    __shared__ int emptyList[64];
    __shared__ int nEmpty;
    __shared__ float4 corr;
    __shared__ float4 redf[4];
    __shared__ int lastFlag;
    const int b = blockIdx.x, tid = threadIdx.x;
    const int t = tid & 63, g = tid >> 6;
    if (tid == 0) nEmpty = 0;
    if (tid < T_N) {
        float4 tt = tboxes[b * T_N + tid];
        tb[tid] = tt;
        ta[tid] = (tt.z - tt.x) * (tt.w - tt.y);
    }

    unsigned long long K = 0ull;
    #pragma unroll 4
    for (int i = 0; i < 16; ++i) {
        unsigned long long k = keys[(((size_t)b * NB + (g * 16 + i)) << 6) | t];
        if (k > K) K = k;
    }
    sh[g][t] = K;
    __syncthreads();
    if (tid < 64) {
        unsigned long long m = sh[0][tid];
        #pragma unroll
        for (int g2 = 1; g2 < 16; ++g2) if (sh[g2][tid] > m) m = sh[g2][tid];
        unsigned int lo32 = (unsigned int)(m & 0xFFFFFFFFull);
        if (lo32 != 0u) winner[tid] = ~lo32;
        else { int i = atomicAdd(&nEmpty, 1); emptyList[i] = tid; }
    }
    __syncthreads();

    const int ne = nEmpty;            // normally 0 (targets with max iou < gate)
    for (int e = 0; e < ne; ++e) {
        const int tt = emptyList[e];
        const float4 tbx = tb[tt];
        const float tar = ta[tt];
        unsigned long long bk = 0ull;
        for (int i = tid; i < A_N; i += 1024) {
            float4 an = anchors[i];
            float a1 = (an.z - an.x) * (an.w - an.y);
            float iou = iou_fast(an, a1, tbx, tar);
            unsigned long long key = ((unsigned long long)__float_as_uint(iou) << 32)
                                   | (unsigned long long)(~(unsigned int)i);
            if (key > bk) bk = key;
        }
        #pragma unroll
        for (int off = 32; off; off >>= 1) {
            unsigned long long o = __shfl_down(bk, off, 64);
            if (o > bk) bk = o;
        }
        if ((tid & 63) == 0) sw[g] = bk;
        __syncthreads();
        if (tid == 0) {
            unsigned long long m = sw[0];
            #pragma unroll
            for (int i = 1; i < 16; ++i) if (sw[i] > m) m = sw[i];
            winner[tt] = ~(unsigned int)(m & 0xFFFFFFFFull);
        }
        __syncthreads();
    }

    // corrections: first wave, dedupe winners (lowest target owns), exact
    // row-argmax recompute for matched target.
    if (tid < 64) {
        const unsigned int wa = winner[tid];
        bool owner = true;
        for (int k = 0; k < 64; ++k) {
            unsigned int o = __shfl(wa, k, 64);
            if (k < tid && o == wa) owner = false;
        }
        const size_t ba = (size_t)b * A_N + wa;
        float d0 = 0.f, d1 = 0.f, d2 = 0.f, d3 = 0.f;
        if (owner && (code[ba] & 128) == 0) {
            const float4 aw = anchors[wa];
            const float aw1 = (aw.z - aw.x) * (aw.w - aw.y);
            unsigned int bb = 0u; int bt = 0;
            for (int s = 0; s < T_N; ++s) {
                float iou = iou_fast(aw, aw1, tb[s], ta[s]);
                unsigned int u = __float_as_uint(iou);
                if (u > bb) { bb = u; bt = s; }
            }
            const float p = conf[ba];
            d0 = conf_term(p, true) - conf_term(p, false);   // f0 cancels k1's term
            d1 = 1.f;
            d2 = bterm_at(bbox[ba], tb[bt]);
            d3 = cls_term(cls + ba * 5, (const float*)cls, ba,
                          tlabels[b * T_N + bt] - 1);
        }
        #pragma unroll
        for (int off = 32; off; off >>= 1) {
            d0 += __shfl_down(d0, off, 64);
            d1 += __shfl_down(d1, off, 64);
            d2 += __shfl_down(d2, off, 64);
            d3 += __shfl_down(d3, off, 64);
        }
        if (tid == 0) corr = make_float4(d0, d1, d2, d3);
    }
    __syncthreads();

    // finalize this image: sum 256 float4 partials + corr
    if (tid < NB) {
        float4 v = partials[(size_t)b * NB + tid];
        #pragma unroll
        for (int off = 32; off; off >>= 1) {
            v.x += __shfl_down(v.x, off, 64);
            v.y += __shfl_down(v.y, off, 64);
            v.z += __shfl_down(v.z, off, 64);
            v.w += __shfl_down(v.w, off, 64);
        }
        if ((tid & 63) == 0) redf[tid >> 6] = v;
    }
    __syncthreads();
    if (tid == 0) {
        float s0 = redf[0].x + redf[1].x + redf[2].x + redf[3].x + corr.x;
        float s1 = redf[0].y + redf[1].y + redf[2].y + redf[3].y + corr.y;
        float s2 = redf[0].z + redf[1].z + redf[2].z + redf[3].z + corr.z;
        float s3 = redf[0].w + redf[1].w + redf[2].w + redf[3].w + corr.w;
        float npos = fmaxf(s1, 1.f);
        // device-coherent writes (atomic path bypasses L1; cross-XCD safe)
        atomicExch(&lossImg[b * 3 + 0], s0 * (1.f / (float)A_N));
        atomicExch(&lossImg[b * 3 + 1], s2 / npos);
        atomicExch(&lossImg[b * 3 + 2], s3 / npos);
        __threadfence();
        unsigned int old = atomicAdd(done, 1u);
        lastFlag = (old == B_N - 1) ? 1 : 0;
    }
    __syncthreads();

    // last image-block averages all 16 images -> out[4]
    if (lastFlag && tid < 64) {
        __threadfence();
        float c = 0.f, bm = 0.f, l = 0.f;
        if (tid < B_N) {
            c  = atomicAdd(&lossImg[tid * 3 + 0], 0.f);   // coherent read
            bm = atomicAdd(&lossImg[tid * 3 + 1], 0.f);
            l  = atomicAdd(&lossImg[tid * 3 + 2], 0.f);
        }
        #pragma unroll
        for (int off = 8; off; off >>= 1) {
            c  += __shfl_down(c,  off, 64);
            bm += __shfl_down(bm, off, 64);
            l  += __shfl_down(l,  off, 64);
        }
        if (tid == 0) {
            c *= (1.f / 16.f); bm *= (1.f / 16.f); l *= (1.f / 16.f);
            out[0] = c + bm + l;
            out[1] = c;
            out[2] = bm;
            out[3] = l;
        }
    }
}

extern "C" void kernel_launch(void* const* d_in, const int* in_sizes, int n_in,
                              void* d_out, int out_size, void* d_ws, size_t ws_size,
                              hipStream_t stream)
{
    const float4* bbox    = (const float4*)d_in[0];
    const float*  conf    = (const float*) d_in[1];
    const float4* cls     = (const float4*)d_in[2];
    const float4* anchors = (const float4*)d_in[3];
    const float4* tboxes  = (const float4*)d_in[4];
    const int*    tlabels = (const int*)   d_in[5];
    float* out = (float*)d_out;

    char* ws = (char*)d_ws;
    unsigned long long* keys  = (unsigned long long*)ws;                   // 2 MiB
    unsigned char*      code  = (unsigned char*)(ws + (2u << 20));         // 1 MiB
    float4*       partials = (float4*)(ws + (3u << 20));                   // 64 KiB
    float*        lossImg  = (float*)(ws + (3u << 20) + (64u << 10));      // 192 B
    unsigned int* done     = (unsigned int*)(ws + (3u << 20) + (64u << 10) + 256);

    k1_main <<<dim3(NB, B_N), 256, 0, stream>>>(anchors, bbox, conf, cls, tboxes,
                                                tlabels, keys, code, partials, done);
    k2_all  <<<B_N, 1024, 0, stream>>>(keys, anchors, bbox, conf, cls, tboxes,
                                       tlabels, code, partials, lossImg, done, out);
}